// Round 6
// baseline (249.374 us; speedup 1.0000x reference)
//
#include <hip/hip_runtime.h>
#include <hip/hip_bf16.h>
#include <stdint.h>

// Problem constants (fixed by the reference setup_inputs)
#define BATCH  16384
#define D_IN   1024
#define M_HID  4096
#define R_LORA 16
#define SCALING 2.0f   // ALPHA/R = 32/16

// R6: k_strip unchanged from R5 (at ~37 B/cyc/CU shared-W L2/L3 BW ceiling;
// 690 cyc/round = 256 MFMA + ~440 W-stream). This round fixes k_wprep:
// old version read W0 at 4 KiB lane stride (32-way line split per wave,
// ~60-90 us latency-serialized). New: 1 block per 32-row group, coalesced
// row reads, LoRA from registers, LDS transpose, coalesced linear write.
#define STRIP    64
#define NTHREADS 512

typedef __bf16 bf16x8 __attribute__((ext_vector_type(8)));
typedef float  f32x16 __attribute__((ext_vector_type(16)));

__device__ __forceinline__ unsigned short f2bf(float f) {
    union { float f; unsigned int u; } c; c.f = f;
    unsigned int u = c.u;
    return (unsigned short)((u + 0x7FFFu + ((u >> 16) & 1u)) >> 16);
}

// ---------------- prep: W_eff -> fragment-ordered bf16 (coalesced) ----------------
// Layout (consumed by k_strip): short-offset n32*32768 + c*256 + rl*8 + j
// holds W_eff[n32*32 + rl][c*8 + j],  c in [0,128), rl in [0,32), j in [0,8).
__global__ __launch_bounds__(256) void k_wprep(
    const float* __restrict__ W0, const float* __restrict__ A,
    const float* __restrict__ Bl, unsigned short* __restrict__ wb)
{
    __shared__ unsigned short T[32][D_IN + 8];    // +8 shorts pad: breaks write-out bank aliasing
    const int n32 = blockIdx.x;                   // 128 blocks
    const int t   = threadIdx.x;                  // 256 threads; lane k-offset = t*4

    // Preload A slice: A[j][t*4 .. t*4+3] for all 16 LoRA rows (coalesced, 64 VGPRs)
    float4 Areg[R_LORA];
#pragma unroll
    for (int j = 0; j < R_LORA; ++j)
        Areg[j] = *(const float4*)(A + j * D_IN + t * 4);

    // 32 rows: coalesced W0 row read + LoRA add + bf16 -> LDS (row-major)
#pragma unroll 4
    for (int r = 0; r < 32; ++r) {
        const int n = n32 * 32 + r;
        float4 v = *(const float4*)(W0 + (size_t)n * D_IN + t * 4);
        const float* brow = Bl + n * R_LORA;      // uniform across lanes -> scalar loads
#pragma unroll
        for (int j = 0; j < R_LORA; ++j) {
            float s = SCALING * brow[j];
            v.x += s * Areg[j].x; v.y += s * Areg[j].y;
            v.z += s * Areg[j].z; v.w += s * Areg[j].w;
        }
        ushort4 o = make_ushort4(f2bf(v.x), f2bf(v.y), f2bf(v.z), f2bf(v.w));
        *(ushort4*)(&T[r][t * 4]) = o;
    }
    __syncthreads();

    // Write out fragment-ordered: 32768 consecutive shorts per block.
    // Thread t writes shorts [t*128, t*128+128) as 16 x uint4 (fully coalesced).
    unsigned short* dst = wb + (size_t)n32 * 32768;
#pragma unroll
    for (int i = 0; i < 16; ++i) {
        int L  = t * 128 + i * 8;
        int c  = L >> 8;                  // = t/2 (i*8 < 256)
        int rl = (L >> 3) & 31;           // = (t&1)*16 + i
        uint4 v = *(const uint4*)(&T[rl][c * 8]);
        *(uint4*)(dst + L) = v;
    }
}

// ---------------- main fused kernel (unchanged from R5) ----------------
__global__ __launch_bounds__(NTHREADS, 2) void k_strip(
    const float* __restrict__ xf, const unsigned short* __restrict__ wb,
    const float* __restrict__ b0, const float* __restrict__ W2,
    const float* __restrict__ b2, float* __restrict__ out)
{
    // x strip, chunk-major: As[c*512 + r*8 + j] = x_bf16[row0+r][c*8+j]
    __shared__ unsigned short As[STRIP * D_IN];   // 128 KiB
    __shared__ float red[8][STRIP];               // 2 KiB cross-wave reduce

    const int tid  = threadIdx.x;
    const int lane = tid & 63;
    const int wave = tid >> 6;
    const int rl   = lane & 31;
    const int half = lane >> 5;
    const int row0 = blockIdx.x * STRIP;

    // ---- phase 1: x fp32 -> bf16 into resident LDS strip ----
    {
        const int r  = tid >> 3;                  // 0..63
        const int c0 = tid & 7;
        const float* xr = xf + (size_t)(row0 + r) * D_IN;
#pragma unroll
        for (int i = 0; i < 16; ++i) {
            int c = i * 8 + c0;
            float4 v0 = *(const float4*)(xr + c * 8);
            float4 v1 = *(const float4*)(xr + c * 8 + 4);
            uint4 o;
            o.x = (unsigned)f2bf(v0.x) | ((unsigned)f2bf(v0.y) << 16);
            o.y = (unsigned)f2bf(v0.z) | ((unsigned)f2bf(v0.w) << 16);
            o.z = (unsigned)f2bf(v1.x) | ((unsigned)f2bf(v1.y) << 16);
            o.w = (unsigned)f2bf(v1.z) | ((unsigned)f2bf(v1.w) << 16);
            *(uint4*)(&As[c * 512 + r * 8]) = o;
        }
    }
    __syncthreads();   // the only barrier before the final reduce

    float rowpart[2][16];
#pragma unroll
    for (int ti = 0; ti < 2; ++ti)
#pragma unroll
        for (int r = 0; r < 16; ++r) rowpart[ti][r] = 0.f;

    // ---- main: 8 passes x (K-loop with zero barriers) ----
    for (int pass = 0; pass < 8; ++pass) {
        const int n0 = wave * 64 + pass * 512;
        const float w2a = W2[n0 + rl],      b0a = b0[n0 + rl];
        const float w2b = W2[n0 + 32 + rl], b0b = b0[n0 + 32 + rl];
        const int n32 = wave * 2 + pass * 16;
        const unsigned short* w0p = wb + (size_t)n32 * 32768 + half * 256 + rl * 8;
        const unsigned short* w1p = w0p + 32768;

        f32x16 acc[2][2] = {};
        bf16x8 wf0[4], wf1[4];
#pragma unroll
        for (int p = 0; p < 4; ++p) {             // distance-4 register prefetch
            wf0[p] = *(const bf16x8*)(w0p + p * 512);
            wf1[p] = *(const bf16x8*)(w1p + p * 512);
        }

#pragma unroll 4
        for (int kk = 0; kk < 64; ++kk) {
            const int cur = kk & 3;
            const int coff = (kk * 2 + half) * 512 + rl * 8;
            bf16x8 af0 = *(const bf16x8*)(&As[coff]);        // rows 0..31
            bf16x8 af1 = *(const bf16x8*)(&As[coff + 256]);  // rows 32..63
            bf16x8 w0c = wf0[cur], w1c = wf1[cur];
            if (kk < 60) {
                wf0[cur] = *(const bf16x8*)(w0p + (kk + 4) * 512);
                wf1[cur] = *(const bf16x8*)(w1p + (kk + 4) * 512);
            }
            acc[0][0] = __builtin_amdgcn_mfma_f32_32x32x16_bf16(af0, w0c, acc[0][0], 0, 0, 0);
            acc[0][1] = __builtin_amdgcn_mfma_f32_32x32x16_bf16(af0, w1c, acc[0][1], 0, 0, 0);
            acc[1][0] = __builtin_amdgcn_mfma_f32_32x32x16_bf16(af1, w0c, acc[1][0], 0, 0, 0);
            acc[1][1] = __builtin_amdgcn_mfma_f32_32x32x16_bf16(af1, w1c, acc[1][1], 0, 0, 0);
        }

        // fold this pass: relu(h + bias) dot W2, accumulate per-lane
#pragma unroll
        for (int ti = 0; ti < 2; ++ti)
#pragma unroll
            for (int r = 0; r < 16; ++r)
                rowpart[ti][r] += fmaxf(acc[ti][0][r] + b0a, 0.f) * w2a
                                + fmaxf(acc[ti][1][r] + b0b, 0.f) * w2b;
    }

    // ---- final: shuffle-reduce over 32 col-lanes, cross-wave sum via LDS ----
    // C/D layout (m74/m101): col = lane&31, row = (r&3) + 8*(r>>2) + 4*half
#pragma unroll
    for (int ti = 0; ti < 2; ++ti)
#pragma unroll
        for (int r = 0; r < 16; ++r) {
            float p = rowpart[ti][r];
#pragma unroll
            for (int m = 1; m <= 16; m <<= 1)
                p += __shfl_xor(p, m, 64);        // stays within each 32-half
            if (rl == 0)
                red[wave][ti * 32 + (r & 3) + 8 * (r >> 2) + 4 * half] = p;
        }
    __syncthreads();
    if (tid < STRIP) {
        float s = b2[0];
#pragma unroll
        for (int w = 0; w < 8; ++w) s += red[w][tid];
        out[row0 + tid] = s;
    }
}

// ---------------- naive fallback (correctness only; ws too small) ----------------
__global__ __launch_bounds__(256) void k_naive(
    const float* __restrict__ x, const float* __restrict__ W0,
    const float* __restrict__ b0, const float* __restrict__ A,
    const float* __restrict__ Bl, const float* __restrict__ W2,
    const float* __restrict__ b2, float* __restrict__ out)
{
    __shared__ float xs[D_IN];
    int b = blockIdx.x;
    for (int d = threadIdx.x; d < D_IN; d += 256) xs[d] = x[(size_t)b * D_IN + d];
    __syncthreads();
    float part = 0.f;
    for (int m = threadIdx.x; m < M_HID; m += 256) {
        float h = b0[m];
        const float* wr = W0 + (size_t)m * D_IN;
        const float* brow = Bl + m * R_LORA;
        for (int d = 0; d < D_IN; ++d) {
            float w = wr[d];
            for (int r = 0; r < R_LORA; ++r) w += SCALING * brow[r] * A[r * D_IN + d];
            h += xs[d] * w;
        }
        part += fmaxf(h, 0.f) * W2[m];
    }
    __shared__ float sred[256];
    sred[threadIdx.x] = part;
    __syncthreads();
    for (int s = 128; s > 0; s >>= 1) {
        if (threadIdx.x < s) sred[threadIdx.x] += sred[threadIdx.x + s];
        __syncthreads();
    }
    if (threadIdx.x == 0) out[b] = sred[0] + b2[0];
}

// ---------------- host ----------------
extern "C" void kernel_launch(void* const* d_in, const int* in_sizes, int n_in,
                              void* d_out, int out_size, void* d_ws, size_t ws_size,
                              hipStream_t stream) {
    const float* x  = (const float*)d_in[0];
    const float* W0 = (const float*)d_in[1];
    const float* b0 = (const float*)d_in[2];
    const float* A  = (const float*)d_in[3];
    const float* Bl = (const float*)d_in[4];
    const float* W2 = (const float*)d_in[5];
    const float* b2 = (const float*)d_in[6];
    float* out = (float*)d_out;

    const size_t wb_bytes = (size_t)M_HID * D_IN * 2;   // 8 MiB fragment-ordered W_eff
    if (ws_size >= wb_bytes) {
        unsigned short* wb = (unsigned short*)d_ws;
        hipLaunchKernelGGL(k_wprep, dim3(M_HID / 32), dim3(256), 0, stream,
                           W0, A, Bl, wb);
        hipLaunchKernelGGL(k_strip, dim3(BATCH / STRIP), dim3(NTHREADS), 0, stream,
                           x, wb, b0, W2, b2, out);
    } else {
        hipLaunchKernelGGL(k_naive, dim3(BATCH), dim3(256), 0, stream,
                           x, W0, b0, A, Bl, W2, b2, out);
    }
}